// Round 4
// baseline (431.724 us; speedup 1.0000x reference)
//
#include <hip/hip_runtime.h>
#include <math.h>

// Problem constants
#define NB   4      // batch
#define CIN  64     // channels everywhere (I=CR=CA=CO=64)
#define HH   48
#define WW   48
#define HW   2304   // 48*48
#define DH   46
#define DW   46
#define DD   2116   // 46*46
#define NHEAD 4
#define HC   16

// ---------------------------------------------------------------------------
// xin[n,o,p] = sum_c W_in[o,c] * x[n,c,p] + b_in[o]
// grid (9 px-tiles, 4 n, 16 oc-groups-of-4), block 256
__global__ __launch_bounds__(256) void k_xin(const float* __restrict__ x,
                                             const float* __restrict__ Win,
                                             const float* __restrict__ bin,
                                             float* __restrict__ xin) {
    int px  = blockIdx.x * 256 + threadIdx.x;   // 0..2303 (exact)
    int n   = blockIdx.y;
    int ocg = blockIdx.z * 4;
    const float* xp = x + (size_t)(n * CIN) * HW + px;
    float a0 = bin[ocg + 0], a1 = bin[ocg + 1], a2 = bin[ocg + 2], a3 = bin[ocg + 3];
    #pragma unroll 8
    for (int ic = 0; ic < CIN; ++ic) {
        float xv = xp[ic * HW];
        a0 += Win[(ocg + 0) * CIN + ic] * xv;
        a1 += Win[(ocg + 1) * CIN + ic] * xv;
        a2 += Win[(ocg + 2) * CIN + ic] * xv;
        a3 += Win[(ocg + 3) * CIN + ic] * xv;
    }
    float* op = xin + (size_t)(n * CIN + ocg) * HW + px;
    op[0] = a0; op[HW] = a1; op[2 * HW] = a2; op[3 * HW] = a3;
}

// ---------------------------------------------------------------------------
// Four 3x3 convs from the same input xin:
//   cv0: q0 = conv(xin, Wq[0], SAME)  -> [n,64,48,48]
//   cv1: k0 = conv(xin, Wk[0], VALID) -> [n,64,46,46]
//   cv2: v0 = conv(xin, Wv[0], VALID)
//   cv3: v2 = conv(xin, Wv[2], VALID)
// grid (36 tiles of 8x8, 4 n, 4 cv), block 256: thread = (och=lane, rowpair=wave)
__global__ __launch_bounds__(256) void k_conv(const float* __restrict__ xin,
                                              const float* __restrict__ Wq,
                                              const float* __restrict__ Wk,
                                              const float* __restrict__ Wv,
                                              float* __restrict__ q0, float* __restrict__ k0,
                                              float* __restrict__ v0, float* __restrict__ v2) {
    __shared__ float sx[16][10][12];   // 16 ic x (8+2) rows x (10 cols, pitch 12 for b128 align)
    int cv = blockIdx.z, n = blockIdx.y;
    int ty = (blockIdx.x / 6) * 8, tx = (blockIdx.x % 6) * 8;
    const float* wb; float* ob; int outw, ioff;
    if (cv == 0)      { wb = Wq;               ob = q0; outw = 48; ioff = -1; }
    else if (cv == 1) { wb = Wk;               ob = k0; outw = 46; ioff = 0;  }
    else if (cv == 2) { wb = Wv;               ob = v0; outw = 46; ioff = 0;  }
    else              { wb = Wv + 2 * CIN * CIN * 9; ob = v2; outw = 46; ioff = 0; }
    int tid = threadIdx.x;
    int och = tid & 63, pg = tid >> 6, r0 = pg * 2;
    float acc[2][8];
    #pragma unroll
    for (int i = 0; i < 2; ++i)
        #pragma unroll
        for (int j = 0; j < 8; ++j) acc[i][j] = 0.f;

    for (int icb = 0; icb < CIN; icb += 16) {
        __syncthreads();
        for (int idx = tid; idx < 1600; idx += 256) {
            int ic = idx / 100; int rem = idx - ic * 100;
            int r = rem / 10;   int cq = rem - r * 10;
            int gy = ty + r + ioff, gx = tx + cq + ioff;
            float v = 0.f;
            if ((unsigned)gy < 48u && (unsigned)gx < 48u)
                v = xin[(size_t)(n * CIN + icb + ic) * HW + gy * WW + gx];
            sx[ic][r][cq] = v;
        }
        __syncthreads();
        for (int ic = 0; ic < 16; ++ic) {
            const float* wp = wb + ((size_t)(och * CIN) + icb + ic) * 9;
            float w[9];
            #pragma unroll
            for (int t = 0; t < 9; ++t) w[t] = wp[t];
            float rows[4][10];
            #pragma unroll
            for (int rr = 0; rr < 4; ++rr)
                #pragma unroll
                for (int cc = 0; cc < 10; ++cc)
                    rows[rr][cc] = sx[ic][r0 + rr][cc];   // wave-broadcast LDS reads
            #pragma unroll
            for (int orow = 0; orow < 2; ++orow)
                #pragma unroll
                for (int dy = 0; dy < 3; ++dy)
                    #pragma unroll
                    for (int dx = 0; dx < 3; ++dx) {
                        float wv_ = w[dy * 3 + dx];
                        #pragma unroll
                        for (int px = 0; px < 8; ++px)
                            acc[orow][px] += wv_ * rows[orow + dy][px + dx];
                    }
        }
    }
    int outsz = outw * outw;
    #pragma unroll
    for (int orow = 0; orow < 2; ++orow) {
        int gy = ty + r0 + orow;
        if (gy >= outw) continue;
        #pragma unroll
        for (int px = 0; px < 8; ++px) {
            int gx = tx + px;
            if (gx < outw)
                ob[(size_t)(n * CIN + och) * outsz + gy * outw + gx] = acc[orow][px];
        }
    }
}

// ---------------------------------------------------------------------------
// Attention branch 0, no-max softmax (scores provably small; exp safe in fp32).
// Q-tile = 128 queries (2 per lane: lane and lane+64) -> each broadcast K/V
// float4 LDS read now feeds 8 FMAs, halving LDS-pipe pressure per FLOP.
// D split across 2 blocks (hb) x 4 waves = 8 slices of 529 float4-groups
// (slices 0-6: 66 groups, slice 7: 67). Per 32-float chunk: coalesced
// global->reg prefetch of the NEXT chunk overlaps compute of the current one
// from a WAVE-PRIVATE double-buffered LDS tile — no block barriers in-loop.
// Pad lanes of the last chunk load zeros: exp(0)=1 -> one scalar l-fix.
// Block partial (exact fp32 O,l sums) written to workspace; k_acomb combines.
__global__ __launch_bounds__(256) void k_attn(const float* __restrict__ q0,
                                              const float* __restrict__ k0,
                                              const float* __restrict__ v0,
                                              float* __restrict__ part) {
    __shared__ float smem[8704];   // staging: Ks[4][2][512] | Vs[4][2][512] (32KB)
                                   // then reused: Os[4][16][128] + Ls[4][128] (34KB)
    int qt = blockIdx.x >> 1, hb = blockIdx.x & 1;
    int h = blockIdx.y, n = blockIdx.z;
    int lane = threadIdx.x & 63, wv = threadIdx.x >> 6;
    const float*  qp = q0 + (size_t)(n * CIN + h * HC) * HW + qt * 128 + lane;
    const float4* K4 = (const float4*)(k0 + (size_t)(n * CIN + h * HC) * DD);
    const float4* V4 = (const float4*)(v0 + (size_t)(n * CIN + h * HC) * DD);
    const int RS4 = DD / 4;             // 529 float4 per channel row

    float qA[16], qB[16], OA[16], OB[16];
    #pragma unroll
    for (int c = 0; c < HC; ++c) {
        qA[c] = qp[c * HW];
        qB[c] = qp[c * HW + 64];
        OA[c] = 0.f; OB[c] = 0.f;
    }
    float lA = 0.f, lB = 0.f;

    int si    = hb * 4 + wv;            // 0..7
    int base4 = si * 66;
    int rem   = (si == 7) ? 3 : 2;      // groups in the 9th (partial) chunk

    float* Kw = smem + wv * 1024;       // this wave's K double-buffer (2x512)
    float* Vw = smem + 4096 + wv * 1024;
    int c0 = lane >> 3;                 // 0..7: this lane stages rows c0, c0+8
    int dq = lane & 7;                  // 0..7: float4 column within chunk

    // prefetch chunk 0 (always full)
    float4 ka, kb, va, vb;
    {
        const float4* kp0 = K4 + c0 * RS4 + base4 + dq;
        const float4* vp0 = V4 + c0 * RS4 + base4 + dq;
        ka = kp0[0]; kb = kp0[8 * RS4];
        va = vp0[0]; vb = vp0[8 * RS4];
    }

    for (int it = 0; it < 9; ++it) {
        int buf = it & 1;
        float4* kd = (float4*)(Kw + buf * 512);
        float4* vd = (float4*)(Vw + buf * 512);
        kd[c0 * 8 + dq] = ka; kd[(c0 + 8) * 8 + dq] = kb;
        vd[c0 * 8 + dq] = va; vd[(c0 + 8) * 8 + dq] = vb;
        __builtin_amdgcn_wave_barrier();

        // prefetch next chunk (global latency hides under compute below)
        if (it < 8) {
            bool ok = (it < 7) || (dq < rem);   // only chunk 8 is partial
            int gi = ok ? (base4 + (it + 1) * 8 + dq) : base4;
            const float4* kp0 = K4 + c0 * RS4 + gi;
            const float4* vp0 = V4 + c0 * RS4 + gi;
            ka = kp0[0]; kb = kp0[8 * RS4];
            va = vp0[0]; vb = vp0[8 * RS4];
            if (!ok) {
                ka.x = ka.y = ka.z = ka.w = 0.f; kb = ka;
                va.x = va.y = va.z = va.w = 0.f; vb = va;
            }
        }

        // compute chunk `it` from LDS (broadcast reads, conflict-free)
        const float4* Kl = (const float4*)(Kw + buf * 512);
        const float4* Vl = (const float4*)(Vw + buf * 512);
        #pragma unroll
        for (int g = 0; g < 8; ++g) {
            float ax = 0.f, ay = 0.f, az = 0.f, aw = 0.f;
            float bx = 0.f, by = 0.f, bz = 0.f, bw = 0.f;
            #pragma unroll
            for (int c = 0; c < 16; ++c) {
                float4 kv = Kl[c * 8 + g];
                ax += qA[c] * kv.x; ay += qA[c] * kv.y;
                az += qA[c] * kv.z; aw += qA[c] * kv.w;
                bx += qB[c] * kv.x; by += qB[c] * kv.y;
                bz += qB[c] * kv.z; bw += qB[c] * kv.w;
            }
            float pa0 = __expf(ax), pa1 = __expf(ay), pa2 = __expf(az), pa3 = __expf(aw);
            float pb0 = __expf(bx), pb1 = __expf(by), pb2 = __expf(bz), pb3 = __expf(bw);
            lA += (pa0 + pa1) + (pa2 + pa3);
            lB += (pb0 + pb1) + (pb2 + pb3);
            #pragma unroll
            for (int c = 0; c < 16; ++c) {
                float4 vvv = Vl[c * 8 + g];
                OA[c] += pa0 * vvv.x + pa1 * vvv.y + pa2 * vvv.z + pa3 * vvv.w;
                OB[c] += pb0 * vvv.x + pb1 * vvv.y + pb2 * vvv.z + pb3 * vvv.w;
            }
        }
    }
    // remove exp(0)=1 contributions of zero-padded lanes in the partial chunk
    float pad = (float)(32 - 4 * rem);
    lA -= pad; lB -= pad;

    // barrier BEFORE smem reuse: other waves may still read their K/V tiles
    __syncthreads();
    float* Os = smem;                   // [4][16][128]
    float* Ls = smem + 8192;            // [4][128]
    #pragma unroll
    for (int c = 0; c < 16; ++c) {
        Os[(wv * 16 + c) * 128 + lane]      = OA[c];
        Os[(wv * 16 + c) * 128 + 64 + lane] = OB[c];
    }
    Ls[wv * 128 + lane]      = lA;
    Ls[wv * 128 + 64 + lane] = lB;
    __syncthreads();

    // write block partial: O[16][128] then l[128]
    float* pb = part + (size_t)((((n * NHEAD + h) * 18 + qt) * 2) + hb) * 2176;
    int q = threadIdx.x & 127, cp = threadIdx.x >> 7;
    #pragma unroll
    for (int j = 0; j < 8; ++j) {
        int c = cp * 8 + j;
        float v = (Os[(0 * 16 + c) * 128 + q] + Os[(1 * 16 + c) * 128 + q])
                + (Os[(2 * 16 + c) * 128 + q] + Os[(3 * 16 + c) * 128 + q]);
        pb[c * 128 + q] = v;
    }
    if (threadIdx.x < 128)
        pb[2048 + q] = (Ls[q] + Ls[128 + q]) + (Ls[256 + q] + Ls[384 + q]);
}

// ---------------------------------------------------------------------------
// Combine the 2 D-half partials and normalize -> a0
// grid (18 qt, 4 h, 4 n), block 256
__global__ __launch_bounds__(256) void k_acomb(const float* __restrict__ part,
                                               float* __restrict__ a0) {
    int qt = blockIdx.x, h = blockIdx.y, n = blockIdx.z;
    const float* p0 = part + (size_t)(((n * NHEAD + h) * 18 + qt) * 2) * 2176;
    const float* p1 = p0 + 2176;
    int q = threadIdx.x & 127, cp = threadIdx.x >> 7;
    float inv = 1.f / (p0[2048 + q] + p1[2048 + q]);
    #pragma unroll
    for (int j = 0; j < 8; ++j) {
        int c = cp * 8 + j;
        float v = (p0[c * 128 + q] + p1[c * 128 + q]) * inv;
        a0[(size_t)(n * CIN + h * HC + c) * HW + qt * 128 + q] = v;
    }
}

// ---------------------------------------------------------------------------
// A2mean[n,c] = mean over 2116 positions of v2[n,c,:]
__global__ __launch_bounds__(256) void k_mean(const float* __restrict__ v2,
                                              float* __restrict__ a2m) {
    int n = blockIdx.x >> 6, c = blockIdx.x & 63;
    const float* p = v2 + (size_t)(n * CIN + c) * DD;
    float s = 0.f;
    for (int d = threadIdx.x; d < DD; d += 256) s += p[d];
    #pragma unroll
    for (int off = 32; off > 0; off >>= 1) s += __shfl_down(s, off);
    __shared__ float red[4];
    int lane = threadIdx.x & 63, wv = threadIdx.x >> 6;
    if (lane == 0) red[wv] = s;
    __syncthreads();
    if (threadIdx.x == 0)
        a2m[blockIdx.x] = (red[0] + red[1] + red[2] + red[3]) * (1.f / 2116.f);
}

// ---------------------------------------------------------------------------
// c2[gi,n,o] = b_gates[g,o] + sum_c Wproj[g,2,o,c] * A2mean[n,c], gi∈{i,g,o}
__global__ __launch_bounds__(256) void k_const2(const float* __restrict__ Wproj,
                                                const float* __restrict__ bg,
                                                const float* __restrict__ a2m,
                                                float* __restrict__ c2) {
    int n = blockIdx.x;
    int t = threadIdx.x;
    if (t >= 192) return;
    int gi = t >> 6, o = t & 63;
    int g = (gi == 0) ? 0 : (gi == 1) ? 2 : 3;
    float acc = bg[g * CIN + o];
    const float* wp = Wproj + ((size_t)(g * 4 + 2) * CIN + o) * CIN;
    for (int c = 0; c < CIN; ++c) acc += wp[c] * a2m[n * CIN + c];
    c2[(gi * NB + n) * CIN + o] = acc;
}

// ---------------------------------------------------------------------------
// Gates + LSTM nonlinearity + output 1x1 conv, fused. Block: (n, 16-px tile).
// thread = (o = lane, wave = px-group-of-4)
__global__ __launch_bounds__(256) void k_gates(const float* __restrict__ a0,
                                               const float* __restrict__ c2,
                                               const float* __restrict__ Wproj,
                                               const float* __restrict__ Wout,
                                               const float* __restrict__ bout,
                                               float* __restrict__ out) {
    __shared__ float a0s[64][16];
    __shared__ float wps[3][64][64];   // [gi][c][o] — lane-consecutive, conflict-free
    __shared__ float hs[16][68];       // [px][c], pitch 68 floats (272B = 17*16B aligned)
    int n = blockIdx.y;
    int p0 = blockIdx.x * 16;
    int tid = threadIdx.x;

    for (int idx = tid; idx < 1024; idx += 256) {
        int c = idx >> 4, px = idx & 15;
        a0s[c][px] = a0[(size_t)(n * CIN + c) * HW + p0 + px];
    }
    for (int idx = tid; idx < 12288; idx += 256) {
        int o = idx & 63; int rest = idx >> 6; int c = rest & 63; int gi = rest >> 6;
        int g = (gi == 0) ? 0 : (gi == 1) ? 2 : 3;
        wps[gi][c][o] = Wproj[((size_t)(g * 4 + 0) * CIN + o) * CIN + c];
    }
    __syncthreads();

    int o = tid & 63, pg = tid >> 6;
    float pi[4], pgt[4], po[4];
    {
        float ci = c2[(0 * NB + n) * CIN + o];
        float cg = c2[(1 * NB + n) * CIN + o];
        float co = c2[(2 * NB + n) * CIN + o];
        #pragma unroll
        for (int j = 0; j < 4; ++j) { pi[j] = ci; pgt[j] = cg; po[j] = co; }
    }
    const float4* a4 = (const float4*)&a0s[0][0];
    #pragma unroll 4
    for (int c = 0; c < 64; ++c) {
        float4 av = a4[c * 4 + pg];               // broadcast
        float w0 = wps[0][c][o], w1 = wps[1][c][o], w2 = wps[2][c][o];
        pi[0]  += w0 * av.x; pi[1]  += w0 * av.y; pi[2]  += w0 * av.z; pi[3]  += w0 * av.w;
        pgt[0] += w1 * av.x; pgt[1] += w1 * av.y; pgt[2] += w1 * av.z; pgt[3] += w1 * av.w;
        po[0]  += w2 * av.x; po[1]  += w2 * av.y; po[2]  += w2 * av.z; po[3]  += w2 * av.w;
    }
    #pragma unroll
    for (int j = 0; j < 4; ++j) {
        float ii = 1.f / (1.f + __expf(-pi[j]));
        float gg = tanhf(pgt[j]);
        float oo = 1.f / (1.f + __expf(-po[j]));
        float cc = ii * gg;
        hs[pg * 4 + j][o] = oo * tanhf(cc);
    }
    __syncthreads();
    // out[n,o,px] = sum_c Wout[o,c] * h[c,px] + bout[o]
    float acc[4];
    float bo = bout[o];
    #pragma unroll
    for (int j = 0; j < 4; ++j) acc[j] = bo;
    const float* wo = Wout + o * CIN;             // L1/L2-cached (16 KB)
    #pragma unroll 2
    for (int cg_ = 0; cg_ < 16; ++cg_) {
        float w0 = wo[cg_ * 4 + 0], w1 = wo[cg_ * 4 + 1], w2 = wo[cg_ * 4 + 2], w3 = wo[cg_ * 4 + 3];
        #pragma unroll
        for (int j = 0; j < 4; ++j) {
            const float4 hv = *(const float4*)&hs[pg * 4 + j][cg_ * 4];
            acc[j] += w0 * hv.x + w1 * hv.y + w2 * hv.z + w3 * hv.w;
        }
    }
    #pragma unroll
    for (int j = 0; j < 4; ++j)
        out[(size_t)(n * CIN + o) * HW + p0 + pg * 4 + j] = acc[j];
}

// ---------------------------------------------------------------------------
extern "C" void kernel_launch(void* const* d_in, const int* in_sizes, int n_in,
                              void* d_out, int out_size, void* d_ws, size_t ws_size,
                              hipStream_t stream) {
    const float* x     = (const float*)d_in[0];
    const float* W_in  = (const float*)d_in[1];
    const float* b_in  = (const float*)d_in[2];
    const float* Wq    = (const float*)d_in[3];
    const float* Wk    = (const float*)d_in[4];
    const float* Wv    = (const float*)d_in[5];
    const float* Wproj = (const float*)d_in[6];
    const float* b_g   = (const float*)d_in[7];
    const float* W_out = (const float*)d_in[8];
    const float* b_out = (const float*)d_in[9];
    float* out = (float*)d_out;

    float* xin  = (float*)d_ws;          // 589824
    float* q0   = xin + 589824;          // 589824
    float* k0   = q0 + 589824;           // 541696
    float* v0   = k0 + 541696;           // 541696
    float* v2   = v0 + 541696;           // 541696
    float* a0   = v2 + 541696;           // 589824
    float* a2m  = a0 + 589824;           // 256
    float* c2   = a2m + 256;             // 768
    float* part = c2 + 768;              // 576*2*2176 = 2506752 (~10 MB)
    // total ~23.6 MB of fp32 workspace

    k_xin   <<<dim3(9, 4, 16), 256, 0, stream>>>(x, W_in, b_in, xin);
    k_conv  <<<dim3(36, 4, 4), 256, 0, stream>>>(xin, Wq, Wk, Wv, q0, k0, v0, v2);
    k_attn  <<<dim3(36, 4, 4), 256, 0, stream>>>(q0, k0, v0, part);
    k_acomb <<<dim3(18, 4, 4), 256, 0, stream>>>(part, a0);
    k_mean  <<<dim3(256), 256, 0, stream>>>(v2, a2m);
    k_const2<<<dim3(4), 256, 0, stream>>>(Wproj, b_g, a2m, c2);
    k_gates <<<dim3(144, 4), 256, 0, stream>>>(a0, c2, Wproj, W_out, b_out, out);
}

// Round 5
// 240.984 us; speedup vs baseline: 1.7915x; 1.7915x over previous
//
#include <hip/hip_runtime.h>
#include <math.h>

// Problem constants
#define NB   4      // batch
#define CIN  64     // channels everywhere (I=CR=CA=CO=64)
#define HH   48
#define WW   48
#define HW   2304   // 48*48
#define DH   46
#define DW   46
#define DD   2116   // 46*46
#define NHEAD 4
#define HC   16
#define NT   136    // padded d-tiles (2176 = 136*16; 60 zero-pads)
#define QTL  144    // q-tiles (2304 = 144*16)

typedef short  s4 __attribute__((ext_vector_type(4)));
typedef float  f4 __attribute__((ext_vector_type(4)));

// ---------------------------------------------------------------------------
// xin[n,o,p] = sum_c W_in[o,c] * x[n,c,p] + b_in[o]
__global__ __launch_bounds__(256) void k_xin(const float* __restrict__ x,
                                             const float* __restrict__ Win,
                                             const float* __restrict__ bin,
                                             float* __restrict__ xin) {
    int px  = blockIdx.x * 256 + threadIdx.x;
    int n   = blockIdx.y;
    int ocg = blockIdx.z * 4;
    const float* xp = x + (size_t)(n * CIN) * HW + px;
    float a0 = bin[ocg + 0], a1 = bin[ocg + 1], a2 = bin[ocg + 2], a3 = bin[ocg + 3];
    #pragma unroll 8
    for (int ic = 0; ic < CIN; ++ic) {
        float xv = xp[ic * HW];
        a0 += Win[(ocg + 0) * CIN + ic] * xv;
        a1 += Win[(ocg + 1) * CIN + ic] * xv;
        a2 += Win[(ocg + 2) * CIN + ic] * xv;
        a3 += Win[(ocg + 3) * CIN + ic] * xv;
    }
    float* op = xin + (size_t)(n * CIN + ocg) * HW + px;
    op[0] = a0; op[HW] = a1; op[2 * HW] = a2; op[3 * HW] = a3;
}

// ---------------------------------------------------------------------------
// Four 3x3 convs from xin (unchanged from round 3).
__global__ __launch_bounds__(256) void k_conv(const float* __restrict__ xin,
                                              const float* __restrict__ Wq,
                                              const float* __restrict__ Wk,
                                              const float* __restrict__ Wv,
                                              float* __restrict__ q0, float* __restrict__ k0,
                                              float* __restrict__ v0, float* __restrict__ v2) {
    __shared__ float sx[16][10][12];
    int cv = blockIdx.z, n = blockIdx.y;
    int ty = (blockIdx.x / 6) * 8, tx = (blockIdx.x % 6) * 8;
    const float* wb; float* ob; int outw, ioff;
    if (cv == 0)      { wb = Wq;               ob = q0; outw = 48; ioff = -1; }
    else if (cv == 1) { wb = Wk;               ob = k0; outw = 46; ioff = 0;  }
    else if (cv == 2) { wb = Wv;               ob = v0; outw = 46; ioff = 0;  }
    else              { wb = Wv + 2 * CIN * CIN * 9; ob = v2; outw = 46; ioff = 0; }
    int tid = threadIdx.x;
    int och = tid & 63, pg = tid >> 6, r0 = pg * 2;
    float acc[2][8];
    #pragma unroll
    for (int i = 0; i < 2; ++i)
        #pragma unroll
        for (int j = 0; j < 8; ++j) acc[i][j] = 0.f;

    for (int icb = 0; icb < CIN; icb += 16) {
        __syncthreads();
        for (int idx = tid; idx < 1600; idx += 256) {
            int ic = idx / 100; int rem = idx - ic * 100;
            int r = rem / 10;   int cq = rem - r * 10;
            int gy = ty + r + ioff, gx = tx + cq + ioff;
            float v = 0.f;
            if ((unsigned)gy < 48u && (unsigned)gx < 48u)
                v = xin[(size_t)(n * CIN + icb + ic) * HW + gy * WW + gx];
            sx[ic][r][cq] = v;
        }
        __syncthreads();
        for (int ic = 0; ic < 16; ++ic) {
            const float* wp = wb + ((size_t)(och * CIN) + icb + ic) * 9;
            float w[9];
            #pragma unroll
            for (int t = 0; t < 9; ++t) w[t] = wp[t];
            float rows[4][10];
            #pragma unroll
            for (int rr = 0; rr < 4; ++rr)
                #pragma unroll
                for (int cc = 0; cc < 10; ++cc)
                    rows[rr][cc] = sx[ic][r0 + rr][cc];
            #pragma unroll
            for (int orow = 0; orow < 2; ++orow)
                #pragma unroll
                for (int dy = 0; dy < 3; ++dy)
                    #pragma unroll
                    for (int dx = 0; dx < 3; ++dx) {
                        float wv_ = w[dy * 3 + dx];
                        #pragma unroll
                        for (int px = 0; px < 8; ++px)
                            acc[orow][px] += wv_ * rows[orow + dy][px + dx];
                    }
        }
    }
    int outsz = outw * outw;
    #pragma unroll
    for (int orow = 0; orow < 2; ++orow) {
        int gy = ty + r0 + orow;
        if (gy >= outw) continue;
        #pragma unroll
        for (int px = 0; px < 8; ++px) {
            int gx = tx + px;
            if (gx < outw)
                ob[(size_t)(n * CIN + och) * outsz + gy * outw + gx] = acc[orow][px];
        }
    }
}

// ---------------------------------------------------------------------------
// Convert q0/k0/v0 fp32 -> MFMA-tiled bf16x2 (hi/lo planes, truncation split).
// Qb tile [q16][c16] (B-frag for QK);  Kb tile [d16][c16] (A-frag for QK);
// Vb tile [c16][d16] (A-frag for PV).  K/V padded with zeros to 136 d-tiles.
// grid (144, 16 nh), block 256.
__global__ __launch_bounds__(256) void k_cvt(const float* __restrict__ q0,
                                             const float* __restrict__ k0,
                                             const float* __restrict__ v0,
                                             unsigned short* __restrict__ Qb,
                                             unsigned short* __restrict__ Kb,
                                             unsigned short* __restrict__ Vb) {
    __shared__ float sm[272];            // 16x16 transpose pad 17
    int bx = blockIdx.x, nh = blockIdx.y;
    int n = nh >> 2, h = nh & 3;
    int t = threadIdx.x;
    // ---- Q tile (qt = bx), transpose [c][q] -> [q][c]
    {
        int c = t >> 4, q = t & 15;
        float val = q0[(size_t)(n * CIN + h * HC + c) * HW + bx * 16 + q];
        sm[c * 17 + q] = val;
        __syncthreads();
        int q2 = t >> 4, c2 = t & 15;
        float v = sm[c2 * 17 + q2];
        unsigned u = __builtin_bit_cast(unsigned, v);
        unsigned short* dst = Qb + (size_t)(nh * QTL + bx) * 512;
        dst[t] = (unsigned short)(u >> 16);
        float lo = v - __builtin_bit_cast(float, u & 0xffff0000u);
        dst[256 + t] = (unsigned short)(__builtin_bit_cast(unsigned, lo) >> 16);
    }
    if (bx < NT) {
        // ---- K tile (dt = bx), transpose [c][d] -> [d][c], zero-pad
        __syncthreads();
        int c = t >> 4, d = t & 15;
        int dgl = bx * 16 + d;
        float kv = (dgl < DD) ? k0[(size_t)(n * CIN + h * HC + c) * DD + dgl] : 0.f;
        sm[c * 17 + d] = kv;
        __syncthreads();
        {
            int d2 = t >> 4, c2 = t & 15;
            float v = sm[c2 * 17 + d2];
            unsigned u = __builtin_bit_cast(unsigned, v);
            unsigned short* dst = Kb + (size_t)(nh * NT + bx) * 512;
            dst[t] = (unsigned short)(u >> 16);
            float lo = v - __builtin_bit_cast(float, u & 0xffff0000u);
            dst[256 + t] = (unsigned short)(__builtin_bit_cast(unsigned, lo) >> 16);
        }
        // ---- V tile: already [c][d] orientation, direct
        {
            float vv = (dgl < DD) ? v0[(size_t)(n * CIN + h * HC + c) * DD + dgl] : 0.f;
            unsigned u = __builtin_bit_cast(unsigned, vv);
            unsigned short* dst = Vb + (size_t)(nh * NT + bx) * 512;
            dst[t] = (unsigned short)(u >> 16);
            float lo = vv - __builtin_bit_cast(float, u & 0xffff0000u);
            dst[256 + t] = (unsigned short)(__builtin_bit_cast(unsigned, lo) >> 16);
        }
    }
}

// ---------------------------------------------------------------------------
// MFMA attention. Wave = (64-q strip, 1/8 of D = 17 d-tiles). Per d-tile,
// per q-tile: S^T[d][q] = KhiQhi+KloQhi+KhiQlo (3 mfma 16x16x16 bf16, exact to
// ~2^-16); exp in-register (no-max softmax, scores provably small); split P
// to bf16x2 per-lane (C/D layout == next B layout for K=16 mfma — no data
// movement); O[c][q] += VhiPh+VloPh+VhiPl. K/V frags prefetched 1 tile ahead
// from L2. Block = 4 waves combine partials via LDS; k_acomb finishes.
// Zero-padded d (60 of them) contribute exp(0)=1 to l -> fixed by -60 later.
// grid (72 = 36 strips x 2 hb, 16 nh), block 256.
__global__ __launch_bounds__(256) void k_mattn(const unsigned short* __restrict__ Qb,
                                               const unsigned short* __restrict__ Kb,
                                               const unsigned short* __restrict__ Vb,
                                               float* __restrict__ part) {
    __shared__ float sO[4][4][256];
    __shared__ float sl[4][4][64];
    int strip = blockIdx.x >> 1, hb = blockIdx.x & 1, nh = blockIdx.y;
    int lane = threadIdx.x & 63, wv = threadIdx.x >> 6;
    int ds = hb * 4 + wv;
    int q16 = lane & 15, quad = lane >> 4;
    int foff = q16 * 16 + quad * 4;          // fragment offset within 256-elem plane

    s4 qh[4], ql[4];
    #pragma unroll
    for (int j = 0; j < 4; ++j) {
        const unsigned short* Qp = Qb + (size_t)(nh * QTL + strip * 4 + j) * 512 + foff;
        qh[j] = *(const s4*)(Qp);
        ql[j] = *(const s4*)(Qp + 256);
    }
    f4 O[4];
    float l[4];
    #pragma unroll
    for (int j = 0; j < 4; ++j) { O[j] = (f4){0.f, 0.f, 0.f, 0.f}; l[j] = 0.f; }

    const unsigned short* Kp = Kb + (size_t)(nh * NT + ds * 17) * 512 + foff;
    const unsigned short* Vp = Vb + (size_t)(nh * NT + ds * 17) * 512 + foff;
    s4 khi = *(const s4*)(Kp);
    s4 klo = *(const s4*)(Kp + 256);
    s4 vhi = *(const s4*)(Vp);
    s4 vlo = *(const s4*)(Vp + 256);

    for (int it = 0; it < 17; ++it) {
        int nxt = (it < 16) ? (it + 1) * 512 : 0;    // last prefetch discarded
        s4 nkhi = *(const s4*)(Kp + nxt);
        s4 nklo = *(const s4*)(Kp + nxt + 256);
        s4 nvhi = *(const s4*)(Vp + nxt);
        s4 nvlo = *(const s4*)(Vp + nxt + 256);

        #pragma unroll
        for (int j = 0; j < 4; ++j) {
            f4 c1 = (f4){0.f, 0.f, 0.f, 0.f};
            c1 = __builtin_amdgcn_mfma_f32_16x16x16bf16_1k(khi, qh[j], c1, 0, 0, 0);
            c1 = __builtin_amdgcn_mfma_f32_16x16x16bf16_1k(klo, qh[j], c1, 0, 0, 0);
            c1 = __builtin_amdgcn_mfma_f32_16x16x16bf16_1k(khi, ql[j], c1, 0, 0, 0);
            float p0 = __expf(c1.x), p1 = __expf(c1.y);
            float p2 = __expf(c1.z), p3 = __expf(c1.w);
            l[j] += (p0 + p1) + (p2 + p3);
            unsigned u0 = __builtin_bit_cast(unsigned, p0);
            unsigned u1 = __builtin_bit_cast(unsigned, p1);
            unsigned u2 = __builtin_bit_cast(unsigned, p2);
            unsigned u3 = __builtin_bit_cast(unsigned, p3);
            s4 ph;
            ph.x = (short)(u0 >> 16); ph.y = (short)(u1 >> 16);
            ph.z = (short)(u2 >> 16); ph.w = (short)(u3 >> 16);
            float r0 = p0 - __builtin_bit_cast(float, u0 & 0xffff0000u);
            float r1 = p1 - __builtin_bit_cast(float, u1 & 0xffff0000u);
            float r2 = p2 - __builtin_bit_cast(float, u2 & 0xffff0000u);
            float r3 = p3 - __builtin_bit_cast(float, u3 & 0xffff0000u);
            s4 pl;
            pl.x = (short)(__builtin_bit_cast(unsigned, r0) >> 16);
            pl.y = (short)(__builtin_bit_cast(unsigned, r1) >> 16);
            pl.z = (short)(__builtin_bit_cast(unsigned, r2) >> 16);
            pl.w = (short)(__builtin_bit_cast(unsigned, r3) >> 16);
            O[j] = __builtin_amdgcn_mfma_f32_16x16x16bf16_1k(vhi, ph, O[j], 0, 0, 0);
            O[j] = __builtin_amdgcn_mfma_f32_16x16x16bf16_1k(vlo, ph, O[j], 0, 0, 0);
            O[j] = __builtin_amdgcn_mfma_f32_16x16x16bf16_1k(vhi, pl, O[j], 0, 0, 0);
        }
        khi = nkhi; klo = nklo; vhi = nvhi; vlo = nvlo;
    }

    // combine the block's 4 wave-partials through LDS
    #pragma unroll
    for (int j = 0; j < 4; ++j) {
        sO[wv][j][(quad * 4 + 0) * 16 + q16] = O[j].x;
        sO[wv][j][(quad * 4 + 1) * 16 + q16] = O[j].y;
        sO[wv][j][(quad * 4 + 2) * 16 + q16] = O[j].z;
        sO[wv][j][(quad * 4 + 3) * 16 + q16] = O[j].w;
        sl[wv][j][quad * 16 + q16] = l[j];
    }
    __syncthreads();
    int t = threadIdx.x;
    float* pb = part + (size_t)((nh * 36 + strip) * 2 + hb) * 1280;
    #pragma unroll
    for (int j = 0; j < 4; ++j)
        pb[j * 256 + t] = (sO[0][j][t] + sO[1][j][t]) + (sO[2][j][t] + sO[3][j][t]);
    {
        int j2 = t >> 6, i2 = t & 63;
        pb[1024 + t] = (sl[0][j2][i2] + sl[1][j2][i2]) + (sl[2][j2][i2] + sl[3][j2][i2]);
    }
}

// ---------------------------------------------------------------------------
// Combine the 2 D-half partials, subtract the 60 pad-exp(0) terms, normalize.
// grid (36, 16 nh), block 256.
__global__ __launch_bounds__(256) void k_acomb(const float* __restrict__ part,
                                               float* __restrict__ a0) {
    int strip = blockIdx.x, nh = blockIdx.y;
    int n = nh >> 2, h = nh & 3;
    const float* b0 = part + (size_t)((nh * 36 + strip) * 2) * 1280;
    const float* b1 = b0 + 1280;
    int t = threadIdx.x;
    int q = t & 15, c = t >> 4;
    #pragma unroll
    for (int j = 0; j < 4; ++j) {
        float lsum = 0.f;
        #pragma unroll
        for (int qd = 0; qd < 4; ++qd)
            lsum += b0[1024 + j * 64 + qd * 16 + q] + b1[1024 + j * 64 + qd * 16 + q];
        float inv = 1.f / (lsum - 60.f);
        float v = (b0[j * 256 + c * 16 + q] + b1[j * 256 + c * 16 + q]) * inv;
        a0[(size_t)(n * CIN + h * HC + c) * HW + strip * 64 + j * 16 + q] = v;
    }
}

// ---------------------------------------------------------------------------
// A2mean[n,c] = mean over 2116 positions of v2[n,c,:]
__global__ __launch_bounds__(256) void k_mean(const float* __restrict__ v2,
                                              float* __restrict__ a2m) {
    int n = blockIdx.x >> 6, c = blockIdx.x & 63;
    const float* p = v2 + (size_t)(n * CIN + c) * DD;
    float s = 0.f;
    for (int d = threadIdx.x; d < DD; d += 256) s += p[d];
    #pragma unroll
    for (int off = 32; off > 0; off >>= 1) s += __shfl_down(s, off);
    __shared__ float red[4];
    int lane = threadIdx.x & 63, wv = threadIdx.x >> 6;
    if (lane == 0) red[wv] = s;
    __syncthreads();
    if (threadIdx.x == 0)
        a2m[blockIdx.x] = (red[0] + red[1] + red[2] + red[3]) * (1.f / 2116.f);
}

// ---------------------------------------------------------------------------
__global__ __launch_bounds__(256) void k_const2(const float* __restrict__ Wproj,
                                                const float* __restrict__ bg,
                                                const float* __restrict__ a2m,
                                                float* __restrict__ c2) {
    int n = blockIdx.x;
    int t = threadIdx.x;
    if (t >= 192) return;
    int gi = t >> 6, o = t & 63;
    int g = (gi == 0) ? 0 : (gi == 1) ? 2 : 3;
    float acc = bg[g * CIN + o];
    const float* wp = Wproj + ((size_t)(g * 4 + 2) * CIN + o) * CIN;
    for (int c = 0; c < CIN; ++c) acc += wp[c] * a2m[n * CIN + c];
    c2[(gi * NB + n) * CIN + o] = acc;
}

// ---------------------------------------------------------------------------
// Gates + LSTM nonlinearity + output 1x1 conv, fused (unchanged).
__global__ __launch_bounds__(256) void k_gates(const float* __restrict__ a0,
                                               const float* __restrict__ c2,
                                               const float* __restrict__ Wproj,
                                               const float* __restrict__ Wout,
                                               const float* __restrict__ bout,
                                               float* __restrict__ out) {
    __shared__ float a0s[64][16];
    __shared__ float wps[3][64][64];
    __shared__ float hs[16][68];
    int n = blockIdx.y;
    int p0 = blockIdx.x * 16;
    int tid = threadIdx.x;

    for (int idx = tid; idx < 1024; idx += 256) {
        int c = idx >> 4, px = idx & 15;
        a0s[c][px] = a0[(size_t)(n * CIN + c) * HW + p0 + px];
    }
    for (int idx = tid; idx < 12288; idx += 256) {
        int o = idx & 63; int rest = idx >> 6; int c = rest & 63; int gi = rest >> 6;
        int g = (gi == 0) ? 0 : (gi == 1) ? 2 : 3;
        wps[gi][c][o] = Wproj[((size_t)(g * 4 + 0) * CIN + o) * CIN + c];
    }
    __syncthreads();

    int o = tid & 63, pg = tid >> 6;
    float pi[4], pgt[4], po[4];
    {
        float ci = c2[(0 * NB + n) * CIN + o];
        float cg = c2[(1 * NB + n) * CIN + o];
        float co = c2[(2 * NB + n) * CIN + o];
        #pragma unroll
        for (int j = 0; j < 4; ++j) { pi[j] = ci; pgt[j] = cg; po[j] = co; }
    }
    const float4* a4 = (const float4*)&a0s[0][0];
    #pragma unroll 4
    for (int c = 0; c < 64; ++c) {
        float4 av = a4[c * 4 + pg];
        float w0 = wps[0][c][o], w1 = wps[1][c][o], w2 = wps[2][c][o];
        pi[0]  += w0 * av.x; pi[1]  += w0 * av.y; pi[2]  += w0 * av.z; pi[3]  += w0 * av.w;
        pgt[0] += w1 * av.x; pgt[1] += w1 * av.y; pgt[2] += w1 * av.z; pgt[3] += w1 * av.w;
        po[0]  += w2 * av.x; po[1]  += w2 * av.y; po[2]  += w2 * av.z; po[3]  += w2 * av.w;
    }
    #pragma unroll
    for (int j = 0; j < 4; ++j) {
        float ii = 1.f / (1.f + __expf(-pi[j]));
        float gg = tanhf(pgt[j]);
        float oo = 1.f / (1.f + __expf(-po[j]));
        float cc = ii * gg;
        hs[pg * 4 + j][o] = oo * tanhf(cc);
    }
    __syncthreads();
    float acc[4];
    float bo = bout[o];
    #pragma unroll
    for (int j = 0; j < 4; ++j) acc[j] = bo;
    const float* wo = Wout + o * CIN;
    #pragma unroll 2
    for (int cg_ = 0; cg_ < 16; ++cg_) {
        float w0 = wo[cg_ * 4 + 0], w1 = wo[cg_ * 4 + 1], w2 = wo[cg_ * 4 + 2], w3 = wo[cg_ * 4 + 3];
        #pragma unroll
        for (int j = 0; j < 4; ++j) {
            const float4 hv = *(const float4*)&hs[pg * 4 + j][cg_ * 4];
            acc[j] += w0 * hv.x + w1 * hv.y + w2 * hv.z + w3 * hv.w;
        }
    }
    #pragma unroll
    for (int j = 0; j < 4; ++j)
        out[(size_t)(n * CIN + o) * HW + p0 + pg * 4 + j] = acc[j];
}

// ---------------------------------------------------------------------------
extern "C" void kernel_launch(void* const* d_in, const int* in_sizes, int n_in,
                              void* d_out, int out_size, void* d_ws, size_t ws_size,
                              hipStream_t stream) {
    const float* x     = (const float*)d_in[0];
    const float* W_in  = (const float*)d_in[1];
    const float* b_in  = (const float*)d_in[2];
    const float* Wq    = (const float*)d_in[3];
    const float* Wk    = (const float*)d_in[4];
    const float* Wv    = (const float*)d_in[5];
    const float* Wproj = (const float*)d_in[6];
    const float* b_g   = (const float*)d_in[7];
    const float* W_out = (const float*)d_in[8];
    const float* b_out = (const float*)d_in[9];
    float* out = (float*)d_out;

    float* xin  = (float*)d_ws;          // 589824
    float* q0   = xin + 589824;          // 589824
    float* k0   = q0 + 589824;           // 541696
    float* v0   = k0 + 541696;           // 541696
    float* v2   = v0 + 541696;           // 541696
    float* a0   = v2 + 541696;           // 589824
    float* a2m  = a0 + 589824;           // 256
    float* c2   = a2m + 256;             // 768
    float* fend = c2 + 768;
    unsigned short* Qb = (unsigned short*)fend;            // 16*144*512 = 1179648 ush
    unsigned short* Kb = Qb + (size_t)16 * QTL * 512;      // 16*136*512 = 1114112 ush
    unsigned short* Vb = Kb + (size_t)16 * NT * 512;       // 1114112 ush
    float* part = (float*)(Vb + (size_t)16 * NT * 512);    // 16*36*2*1280 = 1474560 f
    // total ~26.4 MB of workspace

    k_xin   <<<dim3(9, 4, 16), 256, 0, stream>>>(x, W_in, b_in, xin);
    k_conv  <<<dim3(36, 4, 4), 256, 0, stream>>>(xin, Wq, Wk, Wv, q0, k0, v0, v2);
    k_cvt   <<<dim3(144, 16), 256, 0, stream>>>(q0, k0, v0, Qb, Kb, Vb);
    k_mattn <<<dim3(72, 16), 256, 0, stream>>>(Qb, Kb, Vb, part);
    k_acomb <<<dim3(36, 16), 256, 0, stream>>>(part, a0);
    k_mean  <<<dim3(256), 256, 0, stream>>>(v2, a2m);
    k_const2<<<dim3(4), 256, 0, stream>>>(Wproj, b_g, a2m, c2);
    k_gates <<<dim3(144, 4), 256, 0, stream>>>(a0, c2, Wproj, W_out, b_out, out);
}